// Round 13
// baseline (824.180 us; speedup 1.0000x reference)
//
#include <hip/hip_runtime.h>
#include <stdint.h>

#define NEURONS 512
#define SYN     784
#define TIN     500
#define TP      522
#define TPAD    528
#define BATCH   64
#define NCOL    (BATCH*TPAD)   // 33792
#define XW2     18             // xbT words per (b,*,s): word0 guard, 1..16 data, 17 guard
#define NKK     98             // K iterations (6272 / 64)

typedef int i32x4 __attribute__((ext_vector_type(4)));

#define KEEP(x) asm volatile("" :: "v"(x))

// ---------------------------------------------------------------- A pack
__global__ void k_apack(const int* __restrict__ w, uint2* __restrict__ apk) {
    int u = blockIdx.x * 256 + threadIdx.x;            // 401408 slots
    int half = u & 1, m = (u >> 1) & 15, quad = (u >> 5) & 3;
    int rowblk = (u >> 7) & 31, kk = u >> 12;
    int n = rowblk * 16 + m;
    int s = kk * 8 + quad * 2 + half;
    int wv = w[n * SYN + s];
    uint2 v;
    v.x = (wv < 4)  ? (1u << (8 * wv))       : 0u;
    v.y = (wv >= 4) ? (1u << (8 * (wv - 4))) : 0u;
    apk[u] = v;
}

// ---------------------------------------------------------------- spike bits, transposed
__global__ void k_xbitsT(const float* __restrict__ x, uint32_t* __restrict__ xbT) {
    __shared__ unsigned char nib[16][128];
    int tid = threadIdx.x;
    int r0  = blockIdx.x * 16;
    for (int e = tid; e < 2048; e += 256) {
        int row = e >> 7, q4 = e & 127;
        unsigned char v = 0;
        if (q4 < 125) {
            float4 f = *(const float4*)(x + (size_t)(r0 + row) * TIN + q4 * 4);
            v = (unsigned char)((f.x != 0.f) | ((f.y != 0.f) << 1) |
                                ((f.z != 0.f) << 2) | ((f.w != 0.f) << 3));
        }
        nib[row][q4] = v;
    }
    __syncthreads();
    int row = tid >> 4, d = tid & 15;
    uint64_t u = *(const uint64_t*)&nib[row][d * 8];
    uint32_t wd = 0;
#pragma unroll
    for (int q = 0; q < 8; ++q)
        wd |= ((uint32_t)((u >> (8 * q)) & 0xFull)) << (4 * q);
    if (d == 15) wd &= 0xFFFFFu;
    int grow = r0 + row;
    int b = grow / SYN, s = grow - b * SYN;
    xbT[(size_t)(b * XW2 + 1 + d) * SYN + s] = wd;
    if (d == 0) {
        xbT[(size_t)(b * XW2) * SYN + s] = 0u;
        xbT[(size_t)(b * XW2 + 17) * SYN + s] = 0u;
    }
}

// ---------------------------------------------------------------- B-fragment build
__global__ __launch_bounds__(256) void k_bbuild(
    const uint32_t* __restrict__ xbT,
    const int*      __restrict__ wk,
    uint4*          __restrict__ Bg)
{
    __shared__ uint2 T0[2048];
    __shared__ uint2 T1[1024];
    __shared__ uint2 tapv[21];

    const int tid = threadIdx.x;
    if (tid < 21) {
        uint32_t lo = 0, hi = 0;
        for (int q = 0; q < 4; ++q) {
            lo |= ((uint32_t)wk[q * 21 + tid]) << (8 * q);
            hi |= ((uint32_t)wk[(q + 4) * 21 + tid]) << (8 * q);
        }
        tapv[tid] = make_uint2(lo, hi);
    }
    __syncthreads();
    for (int e = tid; e < 3072; e += 256) {
        int base_t = (e < 2048) ? 0 : 11;
        uint32_t mm = (e < 2048) ? e : (e - 2048);
        uint2 a = make_uint2(0u, 0u);
        while (mm) {
            int p = __builtin_ctz(mm);
            uint2 tv = tapv[base_t + p];
            a.x += tv.x; a.y += tv.y;
            mm &= mm - 1;
        }
        if (e < 2048) T0[e] = a; else T1[e - 2048] = a;
    }

    const int col = blockIdx.x * 64 + (tid >> 2);
    const int sp  = tid & 3;
    int b  = col / TPAD, t = col - b * TPAD;
    int bp = t + 11;
    const uint32_t xbase = (uint32_t)((b * XW2 + (bp >> 5)) * SYN + sp * 2);
    const uint32_t xsh   = (uint32_t)(bp & 31);
    __syncthreads();

    const int kk0 = blockIdx.y * 49, kk1 = kk0 + 49;
    for (int kk = kk0; kk < kk1; ++kk) {
        const uint2* px = (const uint2*)(xbT + xbase + kk * 8);
        uint2 lo = px[0];
        uint2 hi = px[SYN / 2];
        uint32_t w0 = __builtin_amdgcn_alignbit(hi.x, lo.x, xsh) & 0x1FFFFFu;
        uint32_t w1 = __builtin_amdgcn_alignbit(hi.y, lo.y, xsh) & 0x1FFFFFu;
        uint32_t l0 = w0 & 2047u, h0 = w0 >> 11;
        uint32_t l1 = w1 & 2047u, h1 = w1 >> 11;
        uint2 a0 = make_uint2(0u, 0u), a1 = make_uint2(0u, 0u);
        if (l0) { uint2 u = T0[l0]; a0.x += u.x; a0.y += u.y; }
        if (h0) { uint2 v = T1[h0]; a0.x += v.x; a0.y += v.y; }
        if (l1) { uint2 u = T0[l1]; a1.x += u.x; a1.y += u.y; }
        if (h1) { uint2 v = T1[h1]; a1.x += v.x; a1.y += v.y; }
        Bg[(size_t)(kk * NCOL + col) * 4 + sp] = make_uint4(a0.x, a0.y, a1.x, a1.y);
    }
}

// ---------------------------------------------------------------- pure GEMM + argmax (R8 verbatim, verified 190us)
__global__ __launch_bounds__(256, 3) void k_gemm2(
    const i32x4* __restrict__ Apk4,
    const i32x4* __restrict__ Bg4,
    unsigned long long* __restrict__ partial)
{
    __shared__ unsigned long long red[128 * 4];

    const int tid  = threadIdx.x;
    const int lane = tid & 63;
    const int wn   = tid >> 6;
    const int quad = lane >> 4, l15 = lane & 15;

    const int phys   = blockIdx.x;
    const int xcd    = phys & 7;
    const int jb     = phys >> 3;
    const int colblk = xcd * 33 + (jb >> 2);
    const int rowblk = jb & 3;

    const int m0   = rowblk * 128;
    const int col0 = colblk * 128;
    const int rb0  = rowblk * 8;
    const int cb   = col0 + wn * 32 + l15;

    const uint32_t pa0 = (uint32_t)(rb0 * 64 + lane);
    const uint32_t pb0 = (uint32_t)(cb * 4 + quad);

    i32x4 acc[8][2];
#pragma unroll
    for (int i = 0; i < 8; ++i)
#pragma unroll
        for (int jj = 0; jj < 2; ++jj) { i32x4 z = {0, 0, 0, 0}; acc[i][jj] = z; }

    i32x4 afA[8], afB[8], bfA[2], bfB[2];
    bfA[0] = Bg4[pb0];
    bfA[1] = Bg4[pb0 + 64];
    bfB[0] = Bg4[pb0 + (uint32_t)NCOL * 4];
    bfB[1] = Bg4[pb0 + (uint32_t)NCOL * 4 + 64];
#pragma unroll
    for (int i = 0; i < 8; ++i) afA[i] = Apk4[pa0 + i * 64];
#pragma unroll
    for (int i = 0; i < 8; ++i) afB[i] = Apk4[pa0 + 2048 + i * 64];

    for (int kk = 0; kk < NKK - 2; kk += 2) {
#pragma unroll
        for (int i = 0; i < 8; ++i)
#pragma unroll
            for (int jj = 0; jj < 2; ++jj)
                acc[i][jj] = __builtin_amdgcn_mfma_i32_16x16x64_i8(afA[i], bfA[jj], acc[i][jj], 0, 0, 0);
        bfA[0] = Bg4[pb0 + (uint32_t)(kk + 2) * (NCOL * 4)];
        bfA[1] = Bg4[pb0 + (uint32_t)(kk + 2) * (NCOL * 4) + 64];
#pragma unroll
        for (int i = 0; i < 8; ++i) afA[i] = Apk4[pa0 + (uint32_t)(kk + 2) * 2048 + i * 64];
#pragma unroll
        for (int i = 0; i < 8; ++i)
#pragma unroll
            for (int jj = 0; jj < 2; ++jj)
                acc[i][jj] = __builtin_amdgcn_mfma_i32_16x16x64_i8(afB[i], bfB[jj], acc[i][jj], 0, 0, 0);
        bfB[0] = Bg4[pb0 + (uint32_t)(kk + 3) * (NCOL * 4)];
        bfB[1] = Bg4[pb0 + (uint32_t)(kk + 3) * (NCOL * 4) + 64];
#pragma unroll
        for (int i = 0; i < 8; ++i) afB[i] = Apk4[pa0 + (uint32_t)(kk + 3) * 2048 + i * 64];
    }
#pragma unroll
    for (int i = 0; i < 8; ++i)
#pragma unroll
        for (int jj = 0; jj < 2; ++jj)
            acc[i][jj] = __builtin_amdgcn_mfma_i32_16x16x64_i8(afA[i], bfA[jj], acc[i][jj], 0, 0, 0);
#pragma unroll
    for (int i = 0; i < 8; ++i)
#pragma unroll
        for (int jj = 0; jj < 2; ++jj)
            acc[i][jj] = __builtin_amdgcn_mfma_i32_16x16x64_i8(afB[i], bfB[jj], acc[i][jj], 0, 0, 0);

#pragma unroll
    for (int jj = 0; jj < 2; ++jj) {
        unsigned long long bp = 0ull;
#pragma unroll
        for (int i = 0; i < 8; ++i)
#pragma unroll
            for (int r = 0; r < 4; ++r) {
                int grow = m0 + i * 16 + quad * 4 + r;
                unsigned long long pk =
                    (((unsigned long long)(uint32_t)acc[i][jj][r]) << 32) |
                    (unsigned long long)(uint32_t)(511 - grow);
                bp = pk > bp ? pk : bp;
            }
        red[(wn * 32 + jj * 16 + l15) * 4 + quad] = bp;
    }
    __syncthreads();
    if (tid < 128) {
        unsigned long long b = red[tid * 4];
#pragma unroll
        for (int u = 1; u < 4; ++u) {
            unsigned long long v = red[tid * 4 + u];
            b = v > b ? v : b;
        }
        atomicMax(&partial[col0 + tid], b);
    }
}

// ---------------------------------------------------------------- ablation variants (diagnostic)
// MODE 1=MFMA-only  2=loads-only(keep-alive)  3=A-loads+MFMA(noB)  4=B-loads+MFMA(noA)
// Same grid/swizzle/reg-bounds as k_gemm2; write only to dead scratch.
template<int MODE>
__global__ __launch_bounds__(256, 3) void k_abl(
    const i32x4* __restrict__ Apk4,
    const i32x4* __restrict__ Bg4,
    unsigned long long* __restrict__ scratch)
{
    __shared__ unsigned long long red[128 * 4];

    const int tid  = threadIdx.x;
    const int lane = tid & 63;
    const int wn   = tid >> 6;
    const int quad = lane >> 4, l15 = lane & 15;

    const int phys   = blockIdx.x;
    const int xcd    = phys & 7;
    const int jb     = phys >> 3;
    const int colblk = xcd * 33 + (jb >> 2);
    const int rowblk = jb & 3;

    const int m0   = rowblk * 128;
    const int col0 = colblk * 128;
    const int rb0  = rowblk * 8;
    const int cb   = col0 + wn * 32 + l15;

    const uint32_t pa0 = (uint32_t)(rb0 * 64 + lane);
    const uint32_t pb0 = (uint32_t)(cb * 4 + quad);

    i32x4 acc[8][2];
#pragma unroll
    for (int i = 0; i < 8; ++i)
#pragma unroll
        for (int jj = 0; jj < 2; ++jj) { i32x4 z = {0, 0, 0, 0}; acc[i][jj] = z; }

    i32x4 afA[8], afB[8], bfA[2], bfB[2];
    bfA[0] = Bg4[pb0];
    bfA[1] = Bg4[pb0 + 64];
    bfB[0] = Bg4[pb0 + (uint32_t)NCOL * 4];
    bfB[1] = Bg4[pb0 + (uint32_t)NCOL * 4 + 64];
#pragma unroll
    for (int i = 0; i < 8; ++i) afA[i] = Apk4[pa0 + i * 64];
#pragma unroll
    for (int i = 0; i < 8; ++i) afB[i] = Apk4[pa0 + 2048 + i * 64];

    for (int kk = 0; kk < NKK - 2; kk += 2) {
        // ---- phase A compute
        if (MODE != 2) {
#pragma unroll
            for (int i = 0; i < 8; ++i)
#pragma unroll
                for (int jj = 0; jj < 2; ++jj)
                    acc[i][jj] = __builtin_amdgcn_mfma_i32_16x16x64_i8(afA[i], bfA[jj], acc[i][jj], 0, 0, 0);
        } else {
#pragma unroll
            for (int i = 0; i < 8; ++i) KEEP(afA[i]);
            KEEP(bfA[0]); KEEP(bfA[1]);
        }
        // ---- phase A refill (same order as real: B then A)
        if (MODE == 2 || MODE == 4) {
            bfA[0] = Bg4[pb0 + (uint32_t)(kk + 2) * (NCOL * 4)];
            bfA[1] = Bg4[pb0 + (uint32_t)(kk + 2) * (NCOL * 4) + 64];
        }
        if (MODE == 2 || MODE == 3) {
#pragma unroll
            for (int i = 0; i < 8; ++i) afA[i] = Apk4[pa0 + (uint32_t)(kk + 2) * 2048 + i * 64];
        }
        // ---- phase B compute
        if (MODE != 2) {
#pragma unroll
            for (int i = 0; i < 8; ++i)
#pragma unroll
                for (int jj = 0; jj < 2; ++jj)
                    acc[i][jj] = __builtin_amdgcn_mfma_i32_16x16x64_i8(afB[i], bfB[jj], acc[i][jj], 0, 0, 0);
        } else {
#pragma unroll
            for (int i = 0; i < 8; ++i) KEEP(afB[i]);
            KEEP(bfB[0]); KEEP(bfB[1]);
        }
        // ---- phase B refill
        if (MODE == 2 || MODE == 4) {
            bfB[0] = Bg4[pb0 + (uint32_t)(kk + 3) * (NCOL * 4)];
            bfB[1] = Bg4[pb0 + (uint32_t)(kk + 3) * (NCOL * 4) + 64];
        }
        if (MODE == 2 || MODE == 3) {
#pragma unroll
            for (int i = 0; i < 8; ++i) afB[i] = Apk4[pa0 + (uint32_t)(kk + 3) * 2048 + i * 64];
        }
    }
    // tail
    if (MODE != 2) {
#pragma unroll
        for (int i = 0; i < 8; ++i)
#pragma unroll
            for (int jj = 0; jj < 2; ++jj)
                acc[i][jj] = __builtin_amdgcn_mfma_i32_16x16x64_i8(afA[i], bfA[jj], acc[i][jj], 0, 0, 0);
#pragma unroll
        for (int i = 0; i < 8; ++i)
#pragma unroll
            for (int jj = 0; jj < 2; ++jj)
                acc[i][jj] = __builtin_amdgcn_mfma_i32_16x16x64_i8(afB[i], bfB[jj], acc[i][jj], 0, 0, 0);
    } else {
#pragma unroll
        for (int i = 0; i < 8; ++i) { KEEP(afA[i]); KEEP(afB[i]); }
        KEEP(bfA[0]); KEEP(bfA[1]); KEEP(bfB[0]); KEEP(bfB[1]);
    }

    // epilogue -> scratch (keeps all acc live; same shape as real epilogue)
#pragma unroll
    for (int jj = 0; jj < 2; ++jj) {
        unsigned long long bp = 0ull;
#pragma unroll
        for (int i = 0; i < 8; ++i)
#pragma unroll
            for (int r = 0; r < 4; ++r) {
                int grow = m0 + i * 16 + quad * 4 + r;
                unsigned long long pk =
                    (((unsigned long long)(uint32_t)acc[i][jj][r]) << 32) |
                    (unsigned long long)(uint32_t)(511 - grow);
                bp = pk > bp ? pk : bp;
            }
        red[(wn * 32 + jj * 16 + l15) * 4 + quad] = bp;
    }
    __syncthreads();
    if (tid < 128) {
        unsigned long long b = red[tid * 4];
#pragma unroll
        for (int u = 1; u < 4; ++u) {
            unsigned long long v = red[tid * 4 + u];
            b = v > b ? v : b;
        }
        atomicMax(&scratch[col0 + tid], b);
    }
}

// ---------------------------------------------------------------- fused fallback (R0, verified 438us)
__global__ __launch_bounds__(256) void k_gemm_fused(
    const i32x4*    __restrict__ Apk4,
    const uint32_t* __restrict__ xbT,
    const int*      __restrict__ wk,
    unsigned long long* __restrict__ partial)
{
    __shared__ uint2 T0[2048];
    __shared__ uint2 T1[1024];
    __shared__ unsigned long long red[128 * 4];
    __shared__ uint2 tapv[21];

    const int tid  = threadIdx.x;
    const int lane = tid & 63;
    const int wn   = tid >> 6;
    const int quad = lane >> 4, l15 = lane & 15;
    const int m0   = blockIdx.x * 128;
    const int col0 = blockIdx.y * 128;
    const int rb0  = blockIdx.x * 8;

    if (tid < 21) {
        uint32_t lo = 0, hi = 0;
        for (int q = 0; q < 4; ++q) {
            lo |= ((uint32_t)wk[q * 21 + tid]) << (8 * q);
            hi |= ((uint32_t)wk[(q + 4) * 21 + tid]) << (8 * q);
        }
        tapv[tid] = make_uint2(lo, hi);
    }
    __syncthreads();
    for (int e = tid; e < 3072; e += 256) {
        int base_t = (e < 2048) ? 0 : 11;
        uint32_t mm = (e < 2048) ? e : (e - 2048);
        uint2 a = make_uint2(0u, 0u);
        while (mm) {
            int p = __builtin_ctz(mm);
            uint2 tv = tapv[base_t + p];
            a.x += tv.x; a.y += tv.y;
            mm &= mm - 1;
        }
        if (e < 2048) T0[e] = a; else T1[e - 2048] = a;
    }

    uint32_t base[2]; uint32_t sh[2];
#pragma unroll
    for (int j = 0; j < 2; ++j) {
        int c = col0 + wn * 32 + j * 16 + l15;
        int b = c / TPAD, t = c - b * TPAD;
        int bp = t + 11;
        base[j] = (uint32_t)((b * XW2 + (bp >> 5)) * SYN + quad * 2);
        sh[j]   = (uint32_t)(bp & 31);
    }
    __syncthreads();

    i32x4 acc[8][2];
#pragma unroll
    for (int i = 0; i < 8; ++i)
#pragma unroll
        for (int j = 0; j < 2; ++j) { i32x4 z = {0, 0, 0, 0}; acc[i][j] = z; }

    for (int kk = 0; kk < NKK; ++kk) {
        i32x4 af[8];
#pragma unroll
        for (int i = 0; i < 8; ++i)
            af[i] = Apk4[(size_t)(kk * 32 + rb0 + i) * 64 + lane];
        i32x4 bf[2];
#pragma unroll
        for (int j = 0; j < 2; ++j) {
            const uint2* px = (const uint2*)(xbT + base[j] + kk * 8);
            uint2 lo = px[0];
            uint2 hi = px[SYN / 2];
            uint32_t win0 = __builtin_amdgcn_alignbit(hi.x, lo.x, sh[j]) & 0x1FFFFFu;
            uint32_t win1 = __builtin_amdgcn_alignbit(hi.y, lo.y, sh[j]) & 0x1FFFFFu;
            uint2 u0 = T0[win0 & 2047], v0 = T1[win0 >> 11];
            uint2 u1 = T0[win1 & 2047], v1 = T1[win1 >> 11];
            i32x4 bb;
            bb[0] = (int)(u0.x + v0.x); bb[1] = (int)(u0.y + v0.y);
            bb[2] = (int)(u1.x + v1.x); bb[3] = (int)(u1.y + v1.y);
            bf[j] = bb;
        }
#pragma unroll
        for (int i = 0; i < 8; ++i)
#pragma unroll
            for (int j = 0; j < 2; ++j)
                acc[i][j] = __builtin_amdgcn_mfma_i32_16x16x64_i8(af[i], bf[j], acc[i][j], 0, 0, 0);
    }

#pragma unroll
    for (int j = 0; j < 2; ++j) {
        unsigned long long bp = 0ull;
#pragma unroll
        for (int i = 0; i < 8; ++i)
#pragma unroll
            for (int r = 0; r < 4; ++r) {
                int grow = m0 + i * 16 + quad * 4 + r;
                unsigned long long pk =
                    (((unsigned long long)(uint32_t)acc[i][j][r]) << 32) |
                    (unsigned long long)(uint32_t)(511 - grow);
                bp = pk > bp ? pk : bp;
            }
        red[(wn * 32 + j * 16 + l15) * 4 + quad] = bp;
    }
    __syncthreads();
    if (tid < 128) {
        unsigned long long b = red[tid * 4];
#pragma unroll
        for (int u = 1; u < 4; ++u) {
            unsigned long long v = red[tid * 4 + u];
            b = v > b ? v : b;
        }
        atomicMax(&partial[col0 + tid], b);
    }
}

// ---------------------------------------------------------------- fire ballot
__global__ void k_fire(const unsigned long long* __restrict__ partial,
                       int* __restrict__ argT, unsigned long long* __restrict__ fireM) {
    int id   = blockIdx.x * 4 + (threadIdx.x >> 6);   // 576 = 64 b x 9 chunks
    int lane = threadIdx.x & 63;
    int b    = id / 9, ch = id - b * 9;
    int t    = ch * 64 + lane;
    int col  = b * TPAD + (t < TPAD ? t : TPAD - 1);
    unsigned long long pv = partial[col];
    int best = (int)(pv >> 32);
    int arg  = 511 - (int)(pv & 0xFFFFFFFFull);
    argT[id * 64 + lane] = arg;
    unsigned long long f = __ballot((t < TP) && (best > 40));
    if (lane == 0) fireM[id] = f;
}

// ---------------------------------------------------------------- depression walk
__global__ void k_scan(const unsigned long long* __restrict__ fireM,
                       const int* __restrict__ argT, float* __restrict__ out) {
    int b = threadIdx.x;  // 64 lanes = 64 batches
    unsigned long long fm[9];
#pragma unroll
    for (int c = 0; c < 9; ++c) fm[c] = fireM[b * 9 + c];
    unsigned short ts[26];
    int nf = 0, dep = 0;
    for (int c = 0; c < 9; ++c) {
        unsigned long long mm = fm[c];
        int pos = 0;
        while (pos < 64) {
            if (dep > 0) {
                int adv = dep < (64 - pos) ? dep : (64 - pos);
                dep -= adv; pos += adv; mm >>= adv;    // adv <= 21 < 64
                continue;
            }
            if (mm == 0) break;
            int z = __builtin_ctzll(mm);
            pos += z; mm >>= z;
            ts[nf++] = (unsigned short)(c * 64 + pos);
            dep = 21; ++pos; mm >>= 1;
        }
    }
    for (int i = 0; i < nf; ++i) {
        int t = ts[i];
        int a = argT[(b * 9 + (t >> 6)) * 64 + (t & 63)];
        out[(size_t)b * (NEURONS * TP) + (size_t)a * TP + t] = 1.0f;
    }
}

extern "C" void kernel_launch(void* const* d_in, const int* in_sizes, int n_in,
                              void* d_out, int out_size, void* d_ws, size_t ws_size,
                              hipStream_t stream) {
    const float* x      = (const float*)d_in[0];
    const int*   weight = (const int*)d_in[1];
    const int*   wk     = (const int*)d_in[2];

    char* ws = (char*)d_ws;
    uint2*              Apk     = (uint2*)(ws);                        // 3,211,264 B
    uint32_t*           xbT     = (uint32_t*)(ws + 3211264);           // 3,612,672 B
    unsigned long long* partial = (unsigned long long*)(ws + 6823936); //   270,336 B
    int*                argT    = (int*)(ws + 7094272);                //   147,456 B
    unsigned long long* fireM   = (unsigned long long*)(ws + 7241728); //     4,608 B
    uint4*              Bg      = (uint4*)(ws + 7246336);              // 211,746,816 B
    const size_t WS_SPLIT_NEED = 7246336ull + 211746816ull;            // ~219 MB
    // diagnostic scratch: last 270KB of Bg (dead data region by the time variants run)
    unsigned long long* scratch = (unsigned long long*)(ws + WS_SPLIT_NEED - 270336);

    float* out = (float*)d_out;

    hipMemsetAsync(out, 0, (size_t)out_size * 4, stream);
    hipMemsetAsync(partial, 0, NCOL * 8, stream);
    k_apack<<<1568, 256, 0, stream>>>(weight, Apk);
    k_xbitsT<<<3136, 256, 0, stream>>>(x, xbT);
    if (ws_size >= WS_SPLIT_NEED) {
        k_bbuild<<<dim3(528, 2), 256, 0, stream>>>(xbT, wk, Bg);
        k_gemm2<<<1056, 256, 0, stream>>>((const i32x4*)Apk, (const i32x4*)Bg, partial);
        k_fire<<<144, 256, 0, stream>>>(partial, argT, fireM);
        k_scan<<<1, 64, 0, stream>>>(fireM, argT, out);
        // ---- diagnostic ablation matrix (writes only to dead scratch) ----
        k_abl<1><<<1056, 256, 0, stream>>>((const i32x4*)Apk, (const i32x4*)Bg, scratch);
        k_abl<2><<<1056, 256, 0, stream>>>((const i32x4*)Apk, (const i32x4*)Bg, scratch);
        k_abl<3><<<1056, 256, 0, stream>>>((const i32x4*)Apk, (const i32x4*)Bg, scratch);
        k_abl<4><<<1056, 256, 0, stream>>>((const i32x4*)Apk, (const i32x4*)Bg, scratch);
    } else {
        k_gemm_fused<<<dim3(4, NCOL / 128), 256, 0, stream>>>((const i32x4*)Apk, xbT, wk, partial);
        k_fire<<<144, 256, 0, stream>>>(partial, argT, fireM);
        k_scan<<<1, 64, 0, stream>>>(fireM, argT, out);
    }
}

// Round 14
// 423.095 us; speedup vs baseline: 1.9480x; 1.9480x over previous
//
#include <hip/hip_runtime.h>
#include <stdint.h>

#define NEURONS 512
#define SYN     784
#define TIN     500
#define TP      522
#define TPAD    528
#define BATCH   64
#define NCOL    (BATCH*TPAD)   // 33792
#define XW2     18             // xbT words per (b,*,s): word0 guard, 1..16 data, 17 guard
#define NKK     98             // K iterations (6272 / 64)

typedef int i32x4 __attribute__((ext_vector_type(4)));

// inline-asm global load: compiler does NOT track the result -> no auto s_waitcnt.
// We place counted vmcnt manually (T4). asm volatile keeps program order among loads.
__device__ __forceinline__ i32x4 glx4(const i32x4* p) {
    i32x4 r;
    asm volatile("global_load_dwordx4 %0, %1, off" : "=v"(r) : "v"(p));
    return r;
}
// counted wait + scheduler fence (rule #18: MFMA is register-only and can hoist
// past an asm waitcnt; sched_barrier(0) pins it).
#define VMCNT(n) do { asm volatile("s_waitcnt vmcnt(" #n ")" ::: "memory"); \
                      __builtin_amdgcn_sched_barrier(0); } while (0)

// ---------------------------------------------------------------- A pack
// One-hot int8 weights, MFMA-fragment-packed (verified R3/R4).
__global__ void k_apack(const int* __restrict__ w, uint2* __restrict__ apk) {
    int u = blockIdx.x * 256 + threadIdx.x;            // 401408 slots
    int half = u & 1, m = (u >> 1) & 15, quad = (u >> 5) & 3;
    int rowblk = (u >> 7) & 31, kk = u >> 12;
    int n = rowblk * 16 + m;
    int s = kk * 8 + quad * 2 + half;
    int wv = w[n * SYN + s];
    uint2 v;
    v.x = (wv < 4)  ? (1u << (8 * wv))       : 0u;
    v.y = (wv >= 4) ? (1u << (8 * (wv - 4))) : 0u;
    apk[u] = v;
}

// ---------------------------------------------------------------- spike bits, transposed
__global__ void k_xbitsT(const float* __restrict__ x, uint32_t* __restrict__ xbT) {
    __shared__ unsigned char nib[16][128];
    int tid = threadIdx.x;
    int r0  = blockIdx.x * 16;
    for (int e = tid; e < 2048; e += 256) {
        int row = e >> 7, q4 = e & 127;
        unsigned char v = 0;
        if (q4 < 125) {
            float4 f = *(const float4*)(x + (size_t)(r0 + row) * TIN + q4 * 4);
            v = (unsigned char)((f.x != 0.f) | ((f.y != 0.f) << 1) |
                                ((f.z != 0.f) << 2) | ((f.w != 0.f) << 3));
        }
        nib[row][q4] = v;
    }
    __syncthreads();
    int row = tid >> 4, d = tid & 15;
    uint64_t u = *(const uint64_t*)&nib[row][d * 8];
    uint32_t wd = 0;
#pragma unroll
    for (int q = 0; q < 8; ++q)
        wd |= ((uint32_t)((u >> (8 * q)) & 0xFull)) << (4 * q);
    if (d == 15) wd &= 0xFFFFFu;
    int grow = r0 + row;
    int b = grow / SYN, s = grow - b * SYN;
    xbT[(size_t)(b * XW2 + 1 + d) * SYN + s] = wd;
    if (d == 0) {
        xbT[(size_t)(b * XW2) * SYN + s] = 0u;
        xbT[(size_t)(b * XW2 + 17) * SYN + s] = 0u;
    }
}

// ---------------------------------------------------------------- B-fragment build
__global__ __launch_bounds__(256) void k_bbuild(
    const uint32_t* __restrict__ xbT,
    const int*      __restrict__ wk,
    uint4*          __restrict__ Bg)
{
    __shared__ uint2 T0[2048];
    __shared__ uint2 T1[1024];
    __shared__ uint2 tapv[21];

    const int tid = threadIdx.x;
    if (tid < 21) {
        uint32_t lo = 0, hi = 0;
        for (int q = 0; q < 4; ++q) {
            lo |= ((uint32_t)wk[q * 21 + tid]) << (8 * q);
            hi |= ((uint32_t)wk[(q + 4) * 21 + tid]) << (8 * q);
        }
        tapv[tid] = make_uint2(lo, hi);
    }
    __syncthreads();
    for (int e = tid; e < 3072; e += 256) {
        int base_t = (e < 2048) ? 0 : 11;
        uint32_t mm = (e < 2048) ? e : (e - 2048);
        uint2 a = make_uint2(0u, 0u);
        while (mm) {
            int p = __builtin_ctz(mm);
            uint2 tv = tapv[base_t + p];
            a.x += tv.x; a.y += tv.y;
            mm &= mm - 1;
        }
        if (e < 2048) T0[e] = a; else T1[e - 2048] = a;
    }

    const int col = blockIdx.x * 64 + (tid >> 2);
    const int sp  = tid & 3;
    int b  = col / TPAD, t = col - b * TPAD;
    int bp = t + 11;
    const uint32_t xbase = (uint32_t)((b * XW2 + (bp >> 5)) * SYN + sp * 2);
    const uint32_t xsh   = (uint32_t)(bp & 31);
    __syncthreads();

    const int kk0 = blockIdx.y * 49, kk1 = kk0 + 49;
    for (int kk = kk0; kk < kk1; ++kk) {
        const uint2* px = (const uint2*)(xbT + xbase + kk * 8);
        uint2 lo = px[0];
        uint2 hi = px[SYN / 2];
        uint32_t w0 = __builtin_amdgcn_alignbit(hi.x, lo.x, xsh) & 0x1FFFFFu;
        uint32_t w1 = __builtin_amdgcn_alignbit(hi.y, lo.y, xsh) & 0x1FFFFFu;
        uint32_t l0 = w0 & 2047u, h0 = w0 >> 11;
        uint32_t l1 = w1 & 2047u, h1 = w1 >> 11;
        uint2 a0 = make_uint2(0u, 0u), a1 = make_uint2(0u, 0u);
        if (l0) { uint2 u = T0[l0]; a0.x += u.x; a0.y += u.y; }
        if (h0) { uint2 v = T1[h0]; a0.x += v.x; a0.y += v.y; }
        if (l1) { uint2 u = T0[l1]; a1.x += u.x; a1.y += u.y; }
        if (h1) { uint2 v = T1[h1]; a1.x += v.x; a1.y += v.y; }
        Bg[(size_t)(kk * NCOL + col) * 4 + sp] = make_uint4(a0.x, a0.y, a1.x, a1.y);
    }
}

// ---------------------------------------------------------------- pure GEMM + argmax
// R14: R8 structure (verified 190us) with the K-loop loads in inline asm and
// HAND-PLACED counted vmcnt. R13's ablation showed no single stream is the
// wall (all 4 variants < 190us); the cost is the compiler's conservative
// waitcnt draining the just-issued prefetch before each MFMA phase. Here the
// wait is exactly vmcnt(10): wait this phase's 10-operand set, keep the 10
// newest prefetch loads in flight across the MFMA phase (T4; never 0 in-loop).
// Load issue order is fixed (bf then af, phase A set then phase B set) so the
// counts are exact. Tail drains 10 -> 0.
__global__ __launch_bounds__(256, 3) void k_gemm2(
    const i32x4* __restrict__ Apk4,
    const i32x4* __restrict__ Bg4,
    unsigned long long* __restrict__ partial)
{
    __shared__ unsigned long long red[128 * 4];

    const int tid  = threadIdx.x;
    const int lane = tid & 63;
    const int wn   = tid >> 6;
    const int quad = lane >> 4, l15 = lane & 15;

    const int phys   = blockIdx.x;
    const int xcd    = phys & 7;
    const int jb     = phys >> 3;
    const int colblk = xcd * 33 + (jb >> 2);
    const int rowblk = jb & 3;

    const int m0   = rowblk * 128;
    const int col0 = colblk * 128;
    const int rb0  = rowblk * 8;
    const int cb   = col0 + wn * 32 + l15;

    const uint32_t pa0 = (uint32_t)(rb0 * 64 + lane);
    const uint32_t pb0 = (uint32_t)(cb * 4 + quad);

    i32x4 acc[8][2];
#pragma unroll
    for (int i = 0; i < 8; ++i)
#pragma unroll
        for (int jj = 0; jj < 2; ++jj) { i32x4 z = {0, 0, 0, 0}; acc[i][jj] = z; }

    i32x4 afA[8], afB[8], bfA[2], bfB[2];
    // prologue, issue order defines vmcnt counts:
    // [A-set: bfA(2), afA(8)] then [B-set: bfB(2), afB(8)] -> 20 outstanding
    bfA[0] = glx4(Bg4 + pb0);
    bfA[1] = glx4(Bg4 + pb0 + 64);
#pragma unroll
    for (int i = 0; i < 8; ++i) afA[i] = glx4(Apk4 + pa0 + i * 64);
    bfB[0] = glx4(Bg4 + pb0 + (uint32_t)NCOL * 4);
    bfB[1] = glx4(Bg4 + pb0 + (uint32_t)NCOL * 4 + 64);
#pragma unroll
    for (int i = 0; i < 8; ++i) afB[i] = glx4(Apk4 + pa0 + 2048 + i * 64);

    for (int kk = 0; kk < NKK - 2; kk += 2) {
        // A-set ready; B-set (10 newest) stays in flight
        VMCNT(10);
#pragma unroll
        for (int i = 0; i < 8; ++i)
#pragma unroll
            for (int jj = 0; jj < 2; ++jj)
                acc[i][jj] = __builtin_amdgcn_mfma_i32_16x16x64_i8(afA[i], bfA[jj], acc[i][jj], 0, 0, 0);
        // refill A-set for kk+2 (10 loads) -> outstanding 20
        bfA[0] = glx4(Bg4 + pb0 + (uint32_t)(kk + 2) * (NCOL * 4));
        bfA[1] = glx4(Bg4 + pb0 + (uint32_t)(kk + 2) * (NCOL * 4) + 64);
#pragma unroll
        for (int i = 0; i < 8; ++i)
            afA[i] = glx4(Apk4 + pa0 + (uint32_t)(kk + 2) * 2048 + i * 64);
        // B-set ready; new A-refill (10 newest) stays in flight
        VMCNT(10);
#pragma unroll
        for (int i = 0; i < 8; ++i)
#pragma unroll
            for (int jj = 0; jj < 2; ++jj)
                acc[i][jj] = __builtin_amdgcn_mfma_i32_16x16x64_i8(afB[i], bfB[jj], acc[i][jj], 0, 0, 0);
        // refill B-set for kk+3 -> outstanding 20
        bfB[0] = glx4(Bg4 + pb0 + (uint32_t)(kk + 3) * (NCOL * 4));
        bfB[1] = glx4(Bg4 + pb0 + (uint32_t)(kk + 3) * (NCOL * 4) + 64);
#pragma unroll
        for (int i = 0; i < 8; ++i)
            afB[i] = glx4(Apk4 + pa0 + (uint32_t)(kk + 3) * 2048 + i * 64);
    }
    // tail: kk = 96 (A-set, 10 newest fly), then 97 (drain all)
    VMCNT(10);
#pragma unroll
    for (int i = 0; i < 8; ++i)
#pragma unroll
        for (int jj = 0; jj < 2; ++jj)
            acc[i][jj] = __builtin_amdgcn_mfma_i32_16x16x64_i8(afA[i], bfA[jj], acc[i][jj], 0, 0, 0);
    VMCNT(0);
#pragma unroll
    for (int i = 0; i < 8; ++i)
#pragma unroll
        for (int jj = 0; jj < 2; ++jj)
            acc[i][jj] = __builtin_amdgcn_mfma_i32_16x16x64_i8(afB[i], bfB[jj], acc[i][jj], 0, 0, 0);

    // epilogue: per-lane best over its 32 rows, then cross-quad via LDS
#pragma unroll
    for (int jj = 0; jj < 2; ++jj) {
        unsigned long long bp = 0ull;
#pragma unroll
        for (int i = 0; i < 8; ++i)
#pragma unroll
            for (int r = 0; r < 4; ++r) {
                int grow = m0 + i * 16 + quad * 4 + r;
                unsigned long long pk =
                    (((unsigned long long)(uint32_t)acc[i][jj][r]) << 32) |
                    (unsigned long long)(uint32_t)(511 - grow);
                bp = pk > bp ? pk : bp;
            }
        red[(wn * 32 + jj * 16 + l15) * 4 + quad] = bp;
    }
    __syncthreads();
    if (tid < 128) {
        unsigned long long b = red[tid * 4];
#pragma unroll
        for (int u = 1; u < 4; ++u) {
            unsigned long long v = red[tid * 4 + u];
            b = v > b ? v : b;
        }
        atomicMax(&partial[col0 + tid], b);
    }
}

// ---------------------------------------------------------------- fused fallback (R0, verified 438us)
__global__ __launch_bounds__(256) void k_gemm_fused(
    const i32x4*    __restrict__ Apk4,
    const uint32_t* __restrict__ xbT,
    const int*      __restrict__ wk,
    unsigned long long* __restrict__ partial)
{
    __shared__ uint2 T0[2048];
    __shared__ uint2 T1[1024];
    __shared__ unsigned long long red[128 * 4];
    __shared__ uint2 tapv[21];

    const int tid  = threadIdx.x;
    const int lane = tid & 63;
    const int wn   = tid >> 6;
    const int quad = lane >> 4, l15 = lane & 15;
    const int m0   = blockIdx.x * 128;
    const int col0 = blockIdx.y * 128;
    const int rb0  = blockIdx.x * 8;

    if (tid < 21) {
        uint32_t lo = 0, hi = 0;
        for (int q = 0; q < 4; ++q) {
            lo |= ((uint32_t)wk[q * 21 + tid]) << (8 * q);
            hi |= ((uint32_t)wk[(q + 4) * 21 + tid]) << (8 * q);
        }
        tapv[tid] = make_uint2(lo, hi);
    }
    __syncthreads();
    for (int e = tid; e < 3072; e += 256) {
        int base_t = (e < 2048) ? 0 : 11;
        uint32_t mm = (e < 2048) ? e : (e - 2048);
        uint2 a = make_uint2(0u, 0u);
        while (mm) {
            int p = __builtin_ctz(mm);
            uint2 tv = tapv[base_t + p];
            a.x += tv.x; a.y += tv.y;
            mm &= mm - 1;
        }
        if (e < 2048) T0[e] = a; else T1[e - 2048] = a;
    }

    uint32_t base[2]; uint32_t sh[2];
#pragma unroll
    for (int j = 0; j < 2; ++j) {
        int c = col0 + wn * 32 + j * 16 + l15;
        int b = c / TPAD, t = c - b * TPAD;
        int bp = t + 11;
        base[j] = (uint32_t)((b * XW2 + (bp >> 5)) * SYN + quad * 2);
        sh[j]   = (uint32_t)(bp & 31);
    }
    __syncthreads();

    i32x4 acc[8][2];
#pragma unroll
    for (int i = 0; i < 8; ++i)
#pragma unroll
        for (int j = 0; j < 2; ++j) { i32x4 z = {0, 0, 0, 0}; acc[i][j] = z; }

    for (int kk = 0; kk < NKK; ++kk) {
        i32x4 af[8];
#pragma unroll
        for (int i = 0; i < 8; ++i)
            af[i] = Apk4[(size_t)(kk * 32 + rb0 + i) * 64 + lane];
        i32x4 bf[2];
#pragma unroll
        for (int j = 0; j < 2; ++j) {
            const uint2* px = (const uint2*)(xbT + base[j] + kk * 8);
            uint2 lo = px[0];
            uint2 hi = px[SYN / 2];
            uint32_t win0 = __builtin_amdgcn_alignbit(hi.x, lo.x, sh[j]) & 0x1FFFFFu;
            uint32_t win1 = __builtin_amdgcn_alignbit(hi.y, lo.y, sh[j]) & 0x1FFFFFu;
            uint2 u0 = T0[win0 & 2047], v0 = T1[win0 >> 11];
            uint2 u1 = T0[win1 & 2047], v1 = T1[win1 >> 11];
            i32x4 bb;
            bb[0] = (int)(u0.x + v0.x); bb[1] = (int)(u0.y + v0.y);
            bb[2] = (int)(u1.x + v1.x); bb[3] = (int)(u1.y + v1.y);
            bf[j] = bb;
        }
#pragma unroll
        for (int i = 0; i < 8; ++i)
#pragma unroll
            for (int j = 0; j < 2; ++j)
                acc[i][j] = __builtin_amdgcn_mfma_i32_16x16x64_i8(af[i], bf[j], acc[i][j], 0, 0, 0);
    }

#pragma unroll
    for (int j = 0; j < 2; ++j) {
        unsigned long long bp = 0ull;
#pragma unroll
        for (int i = 0; i < 8; ++i)
#pragma unroll
            for (int r = 0; r < 4; ++r) {
                int grow = m0 + i * 16 + quad * 4 + r;
                unsigned long long pk =
                    (((unsigned long long)(uint32_t)acc[i][j][r]) << 32) |
                    (unsigned long long)(uint32_t)(511 - grow);
                bp = pk > bp ? pk : bp;
            }
        red[(wn * 32 + j * 16 + l15) * 4 + quad] = bp;
    }
    __syncthreads();
    if (tid < 128) {
        unsigned long long b = red[tid * 4];
#pragma unroll
        for (int u = 1; u < 4; ++u) {
            unsigned long long v = red[tid * 4 + u];
            b = v > b ? v : b;
        }
        atomicMax(&partial[col0 + tid], b);
    }
}

// ---------------------------------------------------------------- fire ballot
__global__ void k_fire(const unsigned long long* __restrict__ partial,
                       int* __restrict__ argT, unsigned long long* __restrict__ fireM) {
    int id   = blockIdx.x * 4 + (threadIdx.x >> 6);   // 576 = 64 b x 9 chunks
    int lane = threadIdx.x & 63;
    int b    = id / 9, ch = id - b * 9;
    int t    = ch * 64 + lane;
    int col  = b * TPAD + (t < TPAD ? t : TPAD - 1);
    unsigned long long pv = partial[col];
    int best = (int)(pv >> 32);
    int arg  = 511 - (int)(pv & 0xFFFFFFFFull);
    argT[id * 64 + lane] = arg;
    unsigned long long f = __ballot((t < TP) && (best > 40));
    if (lane == 0) fireM[id] = f;
}

// ---------------------------------------------------------------- depression walk
__global__ void k_scan(const unsigned long long* __restrict__ fireM,
                       const int* __restrict__ argT, float* __restrict__ out) {
    int b = threadIdx.x;  // 64 lanes = 64 batches
    unsigned long long fm[9];
#pragma unroll
    for (int c = 0; c < 9; ++c) fm[c] = fireM[b * 9 + c];
    unsigned short ts[26];
    int nf = 0, dep = 0;
    for (int c = 0; c < 9; ++c) {
        unsigned long long mm = fm[c];
        int pos = 0;
        while (pos < 64) {
            if (dep > 0) {
                int adv = dep < (64 - pos) ? dep : (64 - pos);
                dep -= adv; pos += adv; mm >>= adv;    // adv <= 21 < 64
                continue;
            }
            if (mm == 0) break;
            int z = __builtin_ctzll(mm);
            pos += z; mm >>= z;
            ts[nf++] = (unsigned short)(c * 64 + pos);
            dep = 21; ++pos; mm >>= 1;
        }
    }
    for (int i = 0; i < nf; ++i) {
        int t = ts[i];
        int a = argT[(b * 9 + (t >> 6)) * 64 + (t & 63)];
        out[(size_t)b * (NEURONS * TP) + (size_t)a * TP + t] = 1.0f;
    }
}

extern "C" void kernel_launch(void* const* d_in, const int* in_sizes, int n_in,
                              void* d_out, int out_size, void* d_ws, size_t ws_size,
                              hipStream_t stream) {
    const float* x      = (const float*)d_in[0];
    const int*   weight = (const int*)d_in[1];
    const int*   wk     = (const int*)d_in[2];

    char* ws = (char*)d_ws;
    uint2*              Apk     = (uint2*)(ws);                        // 3,211,264 B
    uint32_t*           xbT     = (uint32_t*)(ws + 3211264);           // 3,612,672 B
    unsigned long long* partial = (unsigned long long*)(ws + 6823936); //   270,336 B
    int*                argT    = (int*)(ws + 7094272);                //   147,456 B
    unsigned long long* fireM   = (unsigned long long*)(ws + 7241728); //     4,608 B
    uint4*              Bg      = (uint4*)(ws + 7246336);              // 211,746,816 B
    const size_t WS_SPLIT_NEED = 7246336ull + 211746816ull;            // ~219 MB

    float* out = (float*)d_out;

    hipMemsetAsync(out, 0, (size_t)out_size * 4, stream);
    hipMemsetAsync(partial, 0, NCOL * 8, stream);
    k_apack<<<1568, 256, 0, stream>>>(weight, Apk);
    k_xbitsT<<<3136, 256, 0, stream>>>(x, xbT);
    if (ws_size >= WS_SPLIT_NEED) {
        k_bbuild<<<dim3(528, 2), 256, 0, stream>>>(xbT, wk, Bg);
        k_gemm2<<<1056, 256, 0, stream>>>((const i32x4*)Apk, (const i32x4*)Bg, partial);
    } else {
        k_gemm_fused<<<dim3(4, NCOL / 128), 256, 0, stream>>>((const i32x4*)Apk, xbT, wk, partial);
    }
    k_fire<<<144, 256, 0, stream>>>(partial, argT, fireM);
    k_scan<<<1, 64, 0, stream>>>(fireM, argT, out);
}

// Round 15
// 402.969 us; speedup vs baseline: 2.0453x; 1.0499x over previous
//
#include <hip/hip_runtime.h>
#include <stdint.h>

#define NEURONS 512
#define SYN     784
#define TIN     500
#define TP      522
#define TPAD    528
#define BATCH   64
#define NCOL    (BATCH*TPAD)   // 33792
#define XW2     18             // xbT words per (b,*,s): word0 guard, 1..16 data, 17 guard
#define NKK     98             // K iterations (6272 / 64)

typedef int i32x4 __attribute__((ext_vector_type(4)));

// ---------------------------------------------------------------- prep: A pack + spike bits + partial zero (fused)
// blocks 0..1567: apack (+ partial zeroing); blocks 1568..4703: xbitsT.
__global__ __launch_bounds__(256) void k_prep(
    const int* __restrict__ w, uint2* __restrict__ apk,
    const float* __restrict__ x, uint32_t* __restrict__ xbT,
    unsigned long long* __restrict__ partial)
{
    __shared__ unsigned char nib[16][128];
    const int bid = blockIdx.x, tid = threadIdx.x;
    if (bid < 1568) {
        // One-hot int8 weights, MFMA-fragment-packed (verified R3/R4).
        int u = bid * 256 + tid;                       // 401408 slots
        int half = u & 1, m = (u >> 1) & 15, quad = (u >> 5) & 3;
        int rowblk = (u >> 7) & 31, kk = u >> 12;
        int n = rowblk * 16 + m;
        int s = kk * 8 + quad * 2 + half;
        int wv = w[n * SYN + s];
        uint2 v;
        v.x = (wv < 4)  ? (1u << (8 * wv))       : 0u;
        v.y = (wv >= 4) ? (1u << (8 * (wv - 4))) : 0u;
        apk[u] = v;
        if (u < NCOL) partial[u] = 0ull;               // fused memset(partial)
    } else {
        // xbT[(b*18 + word)*784 + s]; word 0,17 guards; LDS nibble transpose.
        int r0 = (bid - 1568) * 16;                    // 3136 blocks
        for (int e = tid; e < 2048; e += 256) {
            int row = e >> 7, q4 = e & 127;
            unsigned char v = 0;
            if (q4 < 125) {
                float4 f = *(const float4*)(x + (size_t)(r0 + row) * TIN + q4 * 4);
                v = (unsigned char)((f.x != 0.f) | ((f.y != 0.f) << 1) |
                                    ((f.z != 0.f) << 2) | ((f.w != 0.f) << 3));
            }
            nib[row][q4] = v;
        }
        __syncthreads();
        int row = tid >> 4, d = tid & 15;
        uint64_t u = *(const uint64_t*)&nib[row][d * 8];
        uint32_t wd = 0;
#pragma unroll
        for (int q = 0; q < 8; ++q)
            wd |= ((uint32_t)((u >> (8 * q)) & 0xFull)) << (4 * q);
        if (d == 15) wd &= 0xFFFFFu;                   // taus 480..499 only
        int grow = r0 + row;
        int b = grow / SYN, s = grow - b * SYN;
        xbT[(size_t)(b * XW2 + 1 + d) * SYN + s] = wd;
        if (d == 0) {
            xbT[(size_t)(b * XW2) * SYN + s] = 0u;     // guard word 0
            xbT[(size_t)(b * XW2 + 17) * SYN + s] = 0u;// guard word 17
        }
    }
}

// ---------------------------------------------------------------- B-fragment build
__global__ __launch_bounds__(256) void k_bbuild(
    const uint32_t* __restrict__ xbT,
    const int*      __restrict__ wk,
    uint4*          __restrict__ Bg)
{
    __shared__ uint2 T0[2048];
    __shared__ uint2 T1[1024];
    __shared__ uint2 tapv[21];

    const int tid = threadIdx.x;
    if (tid < 21) {
        uint32_t lo = 0, hi = 0;
        for (int q = 0; q < 4; ++q) {
            lo |= ((uint32_t)wk[q * 21 + tid]) << (8 * q);
            hi |= ((uint32_t)wk[(q + 4) * 21 + tid]) << (8 * q);
        }
        tapv[tid] = make_uint2(lo, hi);
    }
    __syncthreads();
    for (int e = tid; e < 3072; e += 256) {
        int base_t = (e < 2048) ? 0 : 11;
        uint32_t mm = (e < 2048) ? e : (e - 2048);
        uint2 a = make_uint2(0u, 0u);
        while (mm) {
            int p = __builtin_ctz(mm);
            uint2 tv = tapv[base_t + p];
            a.x += tv.x; a.y += tv.y;
            mm &= mm - 1;
        }
        if (e < 2048) T0[e] = a; else T1[e - 2048] = a;
    }

    const int col = blockIdx.x * 64 + (tid >> 2);
    const int sp  = tid & 3;
    int b  = col / TPAD, t = col - b * TPAD;
    int bp = t + 11;
    const uint32_t xbase = (uint32_t)((b * XW2 + (bp >> 5)) * SYN + sp * 2);
    const uint32_t xsh   = (uint32_t)(bp & 31);
    __syncthreads();

    const int kk0 = blockIdx.y * 49, kk1 = kk0 + 49;
    for (int kk = kk0; kk < kk1; ++kk) {
        const uint2* px = (const uint2*)(xbT + xbase + kk * 8);
        uint2 lo = px[0];
        uint2 hi = px[SYN / 2];
        uint32_t w0 = __builtin_amdgcn_alignbit(hi.x, lo.x, xsh) & 0x1FFFFFu;
        uint32_t w1 = __builtin_amdgcn_alignbit(hi.y, lo.y, xsh) & 0x1FFFFFu;
        uint32_t l0 = w0 & 2047u, h0 = w0 >> 11;
        uint32_t l1 = w1 & 2047u, h1 = w1 >> 11;
        uint2 a0 = make_uint2(0u, 0u), a1 = make_uint2(0u, 0u);
        if (l0) { uint2 u = T0[l0]; a0.x += u.x; a0.y += u.y; }
        if (h0) { uint2 v = T1[h0]; a0.x += v.x; a0.y += v.y; }
        if (l1) { uint2 u = T0[l1]; a1.x += u.x; a1.y += u.y; }
        if (h1) { uint2 v = T1[h1]; a1.x += v.x; a1.y += v.y; }
        Bg[(size_t)(kk * NCOL + col) * 4 + sp] = make_uint4(a0.x, a0.y, a1.x, a1.y);
    }
}

// ---------------------------------------------------------------- pure GEMM + argmax
// R15: SINGLE-buffered operands, __launch_bounds__(256,4) -> 4 waves/SIMD.
// Register fit: acc 64 AGPR + af 32 + bf 8 + addr ~12 = ~116 unified <= 128
// quantum (m69). TLP (4 waves x 326cy MFMA) replaces the register pipeline for
// latency hiding. Discriminates L1-return-BW (160cy/wave-kk term, no change
// expected) vs latency exposure (should vanish). XCD-sibling swizzle kept.
__global__ __launch_bounds__(256, 4) void k_gemm2(
    const i32x4* __restrict__ Apk4,
    const i32x4* __restrict__ Bg4,
    unsigned long long* __restrict__ partial)
{
    __shared__ unsigned long long red[128 * 4];

    const int tid  = threadIdx.x;
    const int lane = tid & 63;
    const int wn   = tid >> 6;
    const int quad = lane >> 4, l15 = lane & 15;

    const int phys   = blockIdx.x;
    const int xcd    = phys & 7;
    const int jb     = phys >> 3;
    const int colblk = xcd * 33 + (jb >> 2);
    const int rowblk = jb & 3;

    const int m0   = rowblk * 128;
    const int col0 = colblk * 128;
    const int rb0  = rowblk * 8;
    const int cb   = col0 + wn * 32 + l15;

    const uint32_t pa0 = (uint32_t)(rb0 * 64 + lane);
    const uint32_t pb0 = (uint32_t)(cb * 4 + quad);

    i32x4 acc[8][2];
#pragma unroll
    for (int i = 0; i < 8; ++i)
#pragma unroll
        for (int jj = 0; jj < 2; ++jj) { i32x4 z = {0, 0, 0, 0}; acc[i][jj] = z; }

    for (int kk = 0; kk < NKK; ++kk) {
        i32x4 bf0 = Bg4[pb0 + (uint32_t)kk * (NCOL * 4)];
        i32x4 bf1 = Bg4[pb0 + (uint32_t)kk * (NCOL * 4) + 64];
        i32x4 af[8];
#pragma unroll
        for (int i = 0; i < 8; ++i)
            af[i] = Apk4[pa0 + (uint32_t)kk * 2048 + i * 64];
#pragma unroll
        for (int i = 0; i < 8; ++i) {
            acc[i][0] = __builtin_amdgcn_mfma_i32_16x16x64_i8(af[i], bf0, acc[i][0], 0, 0, 0);
            acc[i][1] = __builtin_amdgcn_mfma_i32_16x16x64_i8(af[i], bf1, acc[i][1], 0, 0, 0);
        }
    }

    // epilogue: per-lane best over its 32 rows, then cross-quad via LDS
#pragma unroll
    for (int jj = 0; jj < 2; ++jj) {
        unsigned long long bp = 0ull;
#pragma unroll
        for (int i = 0; i < 8; ++i)
#pragma unroll
            for (int r = 0; r < 4; ++r) {
                int grow = m0 + i * 16 + quad * 4 + r;
                unsigned long long pk =
                    (((unsigned long long)(uint32_t)acc[i][jj][r]) << 32) |
                    (unsigned long long)(uint32_t)(511 - grow);
                bp = pk > bp ? pk : bp;
            }
        red[(wn * 32 + jj * 16 + l15) * 4 + quad] = bp;
    }
    __syncthreads();
    if (tid < 128) {
        unsigned long long b = red[tid * 4];
#pragma unroll
        for (int u = 1; u < 4; ++u) {
            unsigned long long v = red[tid * 4 + u];
            b = v > b ? v : b;
        }
        atomicMax(&partial[col0 + tid], b);
    }
}

// ---------------------------------------------------------------- fire + scan + out-zero (fused)
// One block per batch. Zeroes this batch's out slice (replaces 68MB memset
// dispatch), computes fire masks in LDS (replaces k_fire + argT/fireM round
// trip), then lane 0 does the serial depression walk.
__global__ __launch_bounds__(256) void k_firescan(
    const unsigned long long* __restrict__ partial, float* __restrict__ out)
{
    __shared__ int argL[576];
    __shared__ unsigned long long fm[9];
    const int b = blockIdx.x, tid = threadIdx.x;
    const int lane = tid & 63, wv = tid >> 6;

    // zero this batch's out slice (NEURONS*TP floats = 66816 float4)
    float4* ob = (float4*)(out + (size_t)b * (NEURONS * TP));
    for (int i = tid; i < (NEURONS * TP) / 4; i += 256)
        ob[i] = make_float4(0.f, 0.f, 0.f, 0.f);

    // fire: 9 chunks of 64 t (chunk = p*4 + wave)
#pragma unroll
    for (int p = 0; p < 3; ++p) {
        int chunk = p * 4 + wv;
        if (chunk < 9) {                               // wave-uniform branch
            int t = chunk * 64 + lane;
            int col = b * TPAD + (t < TPAD ? t : TPAD - 1);
            unsigned long long pv = partial[col];
            int best = (int)(pv >> 32);
            argL[t] = 511 - (int)(pv & 0xFFFFFFFFull);
            unsigned long long f = __ballot((t < TP) && (best > 40));
            if (lane == 0) fm[chunk] = f;
        }
    }
    __syncthreads();

    if (tid == 0) {
        unsigned short ts[26];
        int nf = 0, dep = 0;
        for (int c = 0; c < 9; ++c) {
            unsigned long long mm = fm[c];
            int pos = 0;
            while (pos < 64) {
                if (dep > 0) {
                    int adv = dep < (64 - pos) ? dep : (64 - pos);
                    dep -= adv; pos += adv; mm >>= adv;    // adv <= 21 < 64
                    continue;
                }
                if (mm == 0) break;
                int z = __builtin_ctzll(mm);
                pos += z; mm >>= z;
                ts[nf++] = (unsigned short)(c * 64 + pos);
                dep = 21; ++pos; mm >>= 1;
            }
        }
        for (int i = 0; i < nf; ++i) {
            int t = ts[i];
            out[(size_t)b * (NEURONS * TP) + (size_t)argL[t] * TP + t] = 1.0f;
        }
    }
}

// ---------------------------------------------------------------- fused fallback (R0, verified 438us)
__global__ __launch_bounds__(256) void k_gemm_fused(
    const i32x4*    __restrict__ Apk4,
    const uint32_t* __restrict__ xbT,
    const int*      __restrict__ wk,
    unsigned long long* __restrict__ partial)
{
    __shared__ uint2 T0[2048];
    __shared__ uint2 T1[1024];
    __shared__ unsigned long long red[128 * 4];
    __shared__ uint2 tapv[21];

    const int tid  = threadIdx.x;
    const int lane = tid & 63;
    const int wn   = tid >> 6;
    const int quad = lane >> 4, l15 = lane & 15;
    const int m0   = blockIdx.x * 128;
    const int col0 = blockIdx.y * 128;
    const int rb0  = blockIdx.x * 8;

    if (tid < 21) {
        uint32_t lo = 0, hi = 0;
        for (int q = 0; q < 4; ++q) {
            lo |= ((uint32_t)wk[q * 21 + tid]) << (8 * q);
            hi |= ((uint32_t)wk[(q + 4) * 21 + tid]) << (8 * q);
        }
        tapv[tid] = make_uint2(lo, hi);
    }
    __syncthreads();
    for (int e = tid; e < 3072; e += 256) {
        int base_t = (e < 2048) ? 0 : 11;
        uint32_t mm = (e < 2048) ? e : (e - 2048);
        uint2 a = make_uint2(0u, 0u);
        while (mm) {
            int p = __builtin_ctz(mm);
            uint2 tv = tapv[base_t + p];
            a.x += tv.x; a.y += tv.y;
            mm &= mm - 1;
        }
        if (e < 2048) T0[e] = a; else T1[e - 2048] = a;
    }

    uint32_t base[2]; uint32_t sh[2];
#pragma unroll
    for (int j = 0; j < 2; ++j) {
        int c = col0 + wn * 32 + j * 16 + l15;
        int b = c / TPAD, t = c - b * TPAD;
        int bp = t + 11;
        base[j] = (uint32_t)((b * XW2 + (bp >> 5)) * SYN + quad * 2);
        sh[j]   = (uint32_t)(bp & 31);
    }
    __syncthreads();

    i32x4 acc[8][2];
#pragma unroll
    for (int i = 0; i < 8; ++i)
#pragma unroll
        for (int j = 0; j < 2; ++j) { i32x4 z = {0, 0, 0, 0}; acc[i][j] = z; }

    for (int kk = 0; kk < NKK; ++kk) {
        i32x4 af[8];
#pragma unroll
        for (int i = 0; i < 8; ++i)
            af[i] = Apk4[(size_t)(kk * 32 + rb0 + i) * 64 + lane];
        i32x4 bf[2];
#pragma unroll
        for (int j = 0; j < 2; ++j) {
            const uint2* px = (const uint2*)(xbT + base[j] + kk * 8);
            uint2 lo = px[0];
            uint2 hi = px[SYN / 2];
            uint32_t win0 = __builtin_amdgcn_alignbit(hi.x, lo.x, sh[j]) & 0x1FFFFFu;
            uint32_t win1 = __builtin_amdgcn_alignbit(hi.y, lo.y, sh[j]) & 0x1FFFFFu;
            uint2 u0 = T0[win0 & 2047], v0 = T1[win0 >> 11];
            uint2 u1 = T0[win1 & 2047], v1 = T1[win1 >> 11];
            i32x4 bb;
            bb[0] = (int)(u0.x + v0.x); bb[1] = (int)(u0.y + v0.y);
            bb[2] = (int)(u1.x + v1.x); bb[3] = (int)(u1.y + v1.y);
            bf[j] = bb;
        }
#pragma unroll
        for (int i = 0; i < 8; ++i)
#pragma unroll
            for (int j = 0; j < 2; ++j)
                acc[i][j] = __builtin_amdgcn_mfma_i32_16x16x64_i8(af[i], bf[j], acc[i][j], 0, 0, 0);
    }

#pragma unroll
    for (int j = 0; j < 2; ++j) {
        unsigned long long bp = 0ull;
#pragma unroll
        for (int i = 0; i < 8; ++i)
#pragma unroll
            for (int r = 0; r < 4; ++r) {
                int grow = m0 + i * 16 + quad * 4 + r;
                unsigned long long pk =
                    (((unsigned long long)(uint32_t)acc[i][j][r]) << 32) |
                    (unsigned long long)(uint32_t)(511 - grow);
                bp = pk > bp ? pk : bp;
            }
        red[(wn * 32 + j * 16 + l15) * 4 + quad] = bp;
    }
    __syncthreads();
    if (tid < 128) {
        unsigned long long b = red[tid * 4];
#pragma unroll
        for (int u = 1; u < 4; ++u) {
            unsigned long long v = red[tid * 4 + u];
            b = v > b ? v : b;
        }
        atomicMax(&partial[col0 + tid], b);
    }
}

// ---------------------------------------------------------------- fire ballot (fallback path)
__global__ void k_fire(const unsigned long long* __restrict__ partial,
                       int* __restrict__ argT, unsigned long long* __restrict__ fireM) {
    int id   = blockIdx.x * 4 + (threadIdx.x >> 6);
    int lane = threadIdx.x & 63;
    int b    = id / 9, ch = id - b * 9;
    int t    = ch * 64 + lane;
    int col  = b * TPAD + (t < TPAD ? t : TPAD - 1);
    unsigned long long pv = partial[col];
    int best = (int)(pv >> 32);
    int arg  = 511 - (int)(pv & 0xFFFFFFFFull);
    argT[id * 64 + lane] = arg;
    unsigned long long f = __ballot((t < TP) && (best > 40));
    if (lane == 0) fireM[id] = f;
}

// ---------------------------------------------------------------- depression walk (fallback path)
__global__ void k_scan(const unsigned long long* __restrict__ fireM,
                       const int* __restrict__ argT, float* __restrict__ out) {
    int b = threadIdx.x;
    unsigned long long fm[9];
#pragma unroll
    for (int c = 0; c < 9; ++c) fm[c] = fireM[b * 9 + c];
    unsigned short ts[26];
    int nf = 0, dep = 0;
    for (int c = 0; c < 9; ++c) {
        unsigned long long mm = fm[c];
        int pos = 0;
        while (pos < 64) {
            if (dep > 0) {
                int adv = dep < (64 - pos) ? dep : (64 - pos);
                dep -= adv; pos += adv; mm >>= adv;
                continue;
            }
            if (mm == 0) break;
            int z = __builtin_ctzll(mm);
            pos += z; mm >>= z;
            ts[nf++] = (unsigned short)(c * 64 + pos);
            dep = 21; ++pos; mm >>= 1;
        }
    }
    for (int i = 0; i < nf; ++i) {
        int t = ts[i];
        int a = argT[(b * 9 + (t >> 6)) * 64 + (t & 63)];
        out[(size_t)b * (NEURONS * TP) + (size_t)a * TP + t] = 1.0f;
    }
}

extern "C" void kernel_launch(void* const* d_in, const int* in_sizes, int n_in,
                              void* d_out, int out_size, void* d_ws, size_t ws_size,
                              hipStream_t stream) {
    const float* x      = (const float*)d_in[0];
    const int*   weight = (const int*)d_in[1];
    const int*   wk     = (const int*)d_in[2];

    char* ws = (char*)d_ws;
    uint2*              Apk     = (uint2*)(ws);                        // 3,211,264 B
    uint32_t*           xbT     = (uint32_t*)(ws + 3211264);           // 3,612,672 B
    unsigned long long* partial = (unsigned long long*)(ws + 6823936); //   270,336 B
    int*                argT    = (int*)(ws + 7094272);                //   147,456 B
    unsigned long long* fireM   = (unsigned long long*)(ws + 7241728); //     4,608 B
    uint4*              Bg      = (uint4*)(ws + 7246336);              // 211,746,816 B
    const size_t WS_SPLIT_NEED = 7246336ull + 211746816ull;            // ~219 MB

    float* out = (float*)d_out;

    if (ws_size >= WS_SPLIT_NEED) {
        // 4 dispatches total (was 9): prep fuses apack+xbitsT+partial-zero;
        // firescan fuses out-zero+fire+scan.
        k_prep<<<4704, 256, 0, stream>>>(weight, Apk, x, xbT, partial);
        k_bbuild<<<dim3(528, 2), 256, 0, stream>>>(xbT, wk, Bg);
        k_gemm2<<<1056, 256, 0, stream>>>((const i32x4*)Apk, (const i32x4*)Bg, partial);
        k_firescan<<<BATCH, 256, 0, stream>>>(partial, out);
    } else {
        hipMemsetAsync(out, 0, (size_t)out_size * 4, stream);
        hipMemsetAsync(partial, 0, NCOL * 8, stream);
        k_prep<<<4704, 256, 0, stream>>>(weight, Apk, x, xbT, partial);
        k_gemm_fused<<<dim3(4, NCOL / 128), 256, 0, stream>>>((const i32x4*)Apk, xbT, wk, partial);
        k_fire<<<144, 256, 0, stream>>>(partial, argT, fireM);
        k_scan<<<1, 64, 0, stream>>>(fireM, argT, out);
    }
}

// Round 16
// 397.874 us; speedup vs baseline: 2.0715x; 1.0128x over previous
//
#include <hip/hip_runtime.h>
#include <stdint.h>

#define NEURONS 512
#define SYN     784
#define TIN     500
#define TP      522
#define TPAD    528
#define BATCH   64
#define NCOL    (BATCH*TPAD)   // 33792
#define XW2     18             // xbT words per (b,*,s): word0 guard, 1..16 data, 17 guard
#define NKK     98             // K iterations (6272 / 64)

typedef int i32x4 __attribute__((ext_vector_type(4)));

// ---------------------------------------------------------------- prep: A pack + spike bits + partial zero (fused; verified R15)
// blocks 0..1567: apack (+ partial zeroing); blocks 1568..4703: xbitsT.
__global__ __launch_bounds__(256) void k_prep(
    const int* __restrict__ w, uint2* __restrict__ apk,
    const float* __restrict__ x, uint32_t* __restrict__ xbT,
    unsigned long long* __restrict__ partial)
{
    __shared__ unsigned char nib[16][128];
    const int bid = blockIdx.x, tid = threadIdx.x;
    if (bid < 1568) {
        // One-hot int8 weights, MFMA-fragment-packed (verified R3/R4).
        int u = bid * 256 + tid;                       // 401408 slots
        int half = u & 1, m = (u >> 1) & 15, quad = (u >> 5) & 3;
        int rowblk = (u >> 7) & 31, kk = u >> 12;
        int n = rowblk * 16 + m;
        int s = kk * 8 + quad * 2 + half;
        int wv = w[n * SYN + s];
        uint2 v;
        v.x = (wv < 4)  ? (1u << (8 * wv))       : 0u;
        v.y = (wv >= 4) ? (1u << (8 * (wv - 4))) : 0u;
        apk[u] = v;
        if (u < NCOL) partial[u] = 0ull;               // fused memset(partial)
    } else {
        // xbT[(b*18 + word)*784 + s]; word 0,17 guards; LDS nibble transpose.
        int r0 = (bid - 1568) * 16;                    // 3136 blocks
        for (int e = tid; e < 2048; e += 256) {
            int row = e >> 7, q4 = e & 127;
            unsigned char v = 0;
            if (q4 < 125) {
                float4 f = *(const float4*)(x + (size_t)(r0 + row) * TIN + q4 * 4);
                v = (unsigned char)((f.x != 0.f) | ((f.y != 0.f) << 1) |
                                    ((f.z != 0.f) << 2) | ((f.w != 0.f) << 3));
            }
            nib[row][q4] = v;
        }
        __syncthreads();
        int row = tid >> 4, d = tid & 15;
        uint64_t u = *(const uint64_t*)&nib[row][d * 8];
        uint32_t wd = 0;
#pragma unroll
        for (int q = 0; q < 8; ++q)
            wd |= ((uint32_t)((u >> (8 * q)) & 0xFull)) << (4 * q);
        if (d == 15) wd &= 0xFFFFFu;                   // taus 480..499 only
        int grow = r0 + row;
        int b = grow / SYN, s = grow - b * SYN;
        xbT[(size_t)(b * XW2 + 1 + d) * SYN + s] = wd;
        if (d == 0) {
            xbT[(size_t)(b * XW2) * SYN + s] = 0u;     // guard word 0
            xbT[(size_t)(b * XW2 + 17) * SYN + s] = 0u;// guard word 17
        }
    }
}

// ---------------------------------------------------------------- fused GEMM + argmax
// R16: back to the FUSED formulation (R0, verified 265us) -- no Bg materialize,
// no bbuild; per-wave window build feeding MFMA directly. Improvements over R0:
// (a) PREDICATED gathers: p(spike)=0.05 => 58%/60% of T0/T1 indices are 0
//     (exact-zero rows); if(idx) skips the LDS read -- exec-masked lanes issue
//     no request => gather pipe + bank conflicts ~2.4x down (the R0 bottleneck).
// (b) XCD swizzle (xbT 3.6MB + Apk 3.2MB both L2-resident per XCD).
// (c) 32-bit A offsets.
// Rationale: R8..R15 proved the split GEMM is pinned at ~186us by operand bytes
// through the L1 return path regardless of schedule/occupancy; split total =
// bbuild(~60) + 186 + Bg HBM round-trip. Fused pays no Bg and its LDS-gather
// bottleneck has the predication lever the split path lacks.
__global__ __launch_bounds__(256) void k_gemm_fused2(
    const i32x4*    __restrict__ Apk4,
    const uint32_t* __restrict__ xbT,
    const int*      __restrict__ wk,
    unsigned long long* __restrict__ partial)
{
    __shared__ uint2 T0[2048];           // taps 0..10 sums, packed u8 x8 (per weight)
    __shared__ uint2 T1[1024];           // taps 11..20
    __shared__ unsigned long long red[128 * 4];
    __shared__ uint2 tapv[21];

    const int tid  = threadIdx.x;
    const int lane = tid & 63;
    const int wn   = tid >> 6;
    const int quad = lane >> 4, l15 = lane & 15;

    // XCD-sibling swizzle (verified R3): 4 rowblk siblings of a colblk adjacent
    // on one XCD -> xbT/A L2-hot.
    const int phys   = blockIdx.x;
    const int xcd    = phys & 7;
    const int jb     = phys >> 3;
    const int colblk = xcd * 33 + (jb >> 2);   // 0..263
    const int rowblk = jb & 3;

    const int m0   = rowblk * 128;
    const int col0 = colblk * 128;
    const int rb0  = rowblk * 8;

    if (tid < 21) {
        uint32_t lo = 0, hi = 0;
        for (int q = 0; q < 4; ++q) {
            lo |= ((uint32_t)wk[q * 21 + tid]) << (8 * q);
            hi |= ((uint32_t)wk[(q + 4) * 21 + tid]) << (8 * q);
        }
        tapv[tid] = make_uint2(lo, hi);
    }
    __syncthreads();
    for (int e = tid; e < 3072; e += 256) {
        int base_t = (e < 2048) ? 0 : 11;
        uint32_t mm = (e < 2048) ? e : (e - 2048);
        uint2 a = make_uint2(0u, 0u);
        while (mm) {
            int p = __builtin_ctz(mm);
            uint2 tv = tapv[base_t + p];
            a.x += tv.x; a.y += tv.y;
            mm &= mm - 1;
        }
        if (e < 2048) T0[e] = a; else T1[e - 2048] = a;
    }

    uint32_t base[2]; uint32_t sh[2];
#pragma unroll
    for (int j = 0; j < 2; ++j) {
        int c = col0 + wn * 32 + j * 16 + l15;
        int b = c / TPAD, t = c - b * TPAD;
        int bp = t + 11;                 // window covers flat bits bp..bp+20
        base[j] = (uint32_t)((b * XW2 + (bp >> 5)) * SYN + quad * 2);
        sh[j]   = (uint32_t)(bp & 31);
    }
    __syncthreads();

    const uint32_t pa0 = (uint32_t)(rb0 * 64 + lane);

    i32x4 acc[8][2];
#pragma unroll
    for (int i = 0; i < 8; ++i)
#pragma unroll
        for (int j = 0; j < 2; ++j) { i32x4 z = {0, 0, 0, 0}; acc[i][j] = z; }

    for (int kk = 0; kk < NKK; ++kk) {
        i32x4 af[8];
#pragma unroll
        for (int i = 0; i < 8; ++i)
            af[i] = Apk4[pa0 + (uint32_t)kk * 2048 + i * 64];
        i32x4 bf[2];
#pragma unroll
        for (int j = 0; j < 2; ++j) {
            const uint2* px = (const uint2*)(xbT + base[j] + kk * 8);
            uint2 lo = px[0];            // word w  : (s0, s1)
            uint2 hi = px[SYN / 2];      // word w+1: (s0, s1)
            uint32_t win0 = __builtin_amdgcn_alignbit(hi.x, lo.x, sh[j]) & 0x1FFFFFu;
            uint32_t win1 = __builtin_amdgcn_alignbit(hi.y, lo.y, sh[j]) & 0x1FFFFFu;
            uint32_t l0 = win0 & 2047u, h0 = win0 >> 11;
            uint32_t l1 = win1 & 2047u, h1 = win1 >> 11;
            uint2 a0 = make_uint2(0u, 0u), a1 = make_uint2(0u, 0u);
            if (l0) { uint2 u = T0[l0]; a0.x += u.x; a0.y += u.y; }   // T0[0]==0: skip exact
            if (h0) { uint2 v = T1[h0]; a0.x += v.x; a0.y += v.y; }
            if (l1) { uint2 u = T0[l1]; a1.x += u.x; a1.y += u.y; }
            if (h1) { uint2 v = T1[h1]; a1.x += v.x; a1.y += v.y; }
            i32x4 bb;
            bb[0] = (int)a0.x; bb[1] = (int)a0.y;
            bb[2] = (int)a1.x; bb[3] = (int)a1.y;
            bf[j] = bb;
        }
#pragma unroll
        for (int i = 0; i < 8; ++i)
#pragma unroll
            for (int j = 0; j < 2; ++j)
                acc[i][j] = __builtin_amdgcn_mfma_i32_16x16x64_i8(af[i], bf[j], acc[i][j], 0, 0, 0);
    }

    // epilogue: per-lane best over its 32 rows, then cross-quad via LDS
#pragma unroll
    for (int j = 0; j < 2; ++j) {
        unsigned long long bp = 0ull;
#pragma unroll
        for (int i = 0; i < 8; ++i)
#pragma unroll
            for (int r = 0; r < 4; ++r) {
                int grow = m0 + i * 16 + quad * 4 + r;
                unsigned long long pk =
                    (((unsigned long long)(uint32_t)acc[i][j][r]) << 32) |
                    (unsigned long long)(uint32_t)(511 - grow);
                bp = pk > bp ? pk : bp;
            }
        red[(wn * 32 + j * 16 + l15) * 4 + quad] = bp;
    }
    __syncthreads();
    if (tid < 128) {
        unsigned long long b = red[tid * 4];
#pragma unroll
        for (int u = 1; u < 4; ++u) {
            unsigned long long v = red[tid * 4 + u];
            b = v > b ? v : b;
        }
        atomicMax(&partial[col0 + tid], b);
    }
}

// ---------------------------------------------------------------- fire + scan + out-zero (fused; verified R15)
__global__ __launch_bounds__(256) void k_firescan(
    const unsigned long long* __restrict__ partial, float* __restrict__ out)
{
    __shared__ int argL[576];
    __shared__ unsigned long long fm[9];
    const int b = blockIdx.x, tid = threadIdx.x;
    const int lane = tid & 63, wv = tid >> 6;

    // zero this batch's out slice (NEURONS*TP floats = 66816 float4)
    float4* ob = (float4*)(out + (size_t)b * (NEURONS * TP));
    for (int i = tid; i < (NEURONS * TP) / 4; i += 256)
        ob[i] = make_float4(0.f, 0.f, 0.f, 0.f);

    // fire: 9 chunks of 64 t (chunk = p*4 + wave)
#pragma unroll
    for (int p = 0; p < 3; ++p) {
        int chunk = p * 4 + wv;
        if (chunk < 9) {                               // wave-uniform branch
            int t = chunk * 64 + lane;
            int col = b * TPAD + (t < TPAD ? t : TPAD - 1);
            unsigned long long pv = partial[col];
            int best = (int)(pv >> 32);
            argL[t] = 511 - (int)(pv & 0xFFFFFFFFull);
            unsigned long long f = __ballot((t < TP) && (best > 40));
            if (lane == 0) fm[chunk] = f;
        }
    }
    __syncthreads();

    if (tid == 0) {
        unsigned short ts[26];
        int nf = 0, dep = 0;
        for (int c = 0; c < 9; ++c) {
            unsigned long long mm = fm[c];
            int pos = 0;
            while (pos < 64) {
                if (dep > 0) {
                    int adv = dep < (64 - pos) ? dep : (64 - pos);
                    dep -= adv; pos += adv; mm >>= adv;    // adv <= 21 < 64
                    continue;
                }
                if (mm == 0) break;
                int z = __builtin_ctzll(mm);
                pos += z; mm >>= z;
                ts[nf++] = (unsigned short)(c * 64 + pos);
                dep = 21; ++pos; mm >>= 1;
            }
        }
        for (int i = 0; i < nf; ++i) {
            int t = ts[i];
            out[(size_t)b * (NEURONS * TP) + (size_t)argL[t] * TP + t] = 1.0f;
        }
    }
}

extern "C" void kernel_launch(void* const* d_in, const int* in_sizes, int n_in,
                              void* d_out, int out_size, void* d_ws, size_t ws_size,
                              hipStream_t stream) {
    const float* x      = (const float*)d_in[0];
    const int*   weight = (const int*)d_in[1];
    const int*   wk     = (const int*)d_in[2];

    char* ws = (char*)d_ws;
    uint2*              Apk     = (uint2*)(ws);                        // 3,211,264 B
    uint32_t*           xbT     = (uint32_t*)(ws + 3211264);           // 3,612,672 B
    unsigned long long* partial = (unsigned long long*)(ws + 6823936); //   270,336 B
    // total ws need: 7,094,272 B

    float* out = (float*)d_out;

    // 3 dispatches: prep (apack + xbitsT + partial-zero), fused GEMM, firescan.
    k_prep<<<4704, 256, 0, stream>>>(weight, Apk, x, xbT, partial);
    k_gemm_fused2<<<1056, 256, 0, stream>>>((const i32x4*)Apk, xbT, wk, partial);
    k_firescan<<<BATCH, 256, 0, stream>>>(partial, out);
}